// Round 5
// baseline (510.280 us; speedup 1.0000x reference)
//
#include <hip/hip_runtime.h>

// EdgeVar R12b: resubmit of R12 (infra failure last round, no kernel signal).
// R8's exact fused structure (the established optimum) with finalize merged
// into fused via last-block-done. 2 dispatches total.
// Post-mortems R2-R11 established:
//   - The wall is L2 random-request rate: 2E = 25.6M lane-gathers ~= 122us
//     pure-gather floor (R7). Request-count bound: record size doesn't matter.
//   - MLP matters: <8 outstanding gathers/thread starves the pipe (R9: +15us).
//   - Residency matters: 5000 waves vs 8192 cost +13us (R10) -- need the full
//     4 blocks/CU = 32 waves/CU. Grid MUST be 1024 x 512.
//   - Dynamic work stealing loses: same-address counter RMWs serialize 1024
//     waves/counter (R11: +55us). Static grid-stride stays.
//   - Tail arithmetic (R11 post-mortem): the 106-block straggler iteration
//     keeps ~430K lane-requests in flight -> L2 stays saturated -> tail costs
//     ~2us, not worth touching. R8's loop is AT the request floor.
//   - LDS hist atomics + boundary search ride ~free on the LDS pipe (R5).
//   - Separate passes (R7: +30us) and bucket-sorting (R3/R6: +100us) lose.
// R12 delta: last block (device-scope done counter) re-reads gsum/gcnt via
// atomicAdd(p,0) (cross-XCD coherent) and writes the mean directly. Saves
// the 1-block finalize kernel + its dispatch gap (~8us predicted).
// No spin-waits anywhere: every block increments done once and exits, so
// the pattern cannot deadlock regardless of scheduling order.

typedef int iv4 __attribute__((ext_vector_type(4)));
typedef unsigned int u32;

#define GBINS 1024

__device__ __forceinline__ int find_graph(int v, const int* __restrict__ ss, float scale) {
    int g = (int)((float)v * scale);       // ~floor(v*G/N); off by a few
    g = min(g, GBINS - 1);
    while (v < ss[g]) --g;                 // ss[0]=0 guards bottom
    while (v >= ss[g + 1]) ++g;            // ss[GBINS]=N guards top
    return g;
}

// startg[1025] from sorted batch_ids; also zeros gsum/gcnt/done (replaces memset).
__global__ void prep(const int* __restrict__ batch, int* __restrict__ startg,
                     float* __restrict__ gsum, u32* __restrict__ gcnt,
                     u32* __restrict__ done, int N) {
    const int i = blockIdx.x * blockDim.x + threadIdx.x;
    if (i == 0) *done = 0u;                // graph-replay safe reset
    if (i < GBINS) { gsum[i] = 0.f; gcnt[i] = 0u; }
    if (i >= N) return;
    const int b = batch[i];
    if (i == 0) { for (int g = 0; g <= b; ++g) startg[g] = 0; }
    else { const int a = batch[i - 1]; for (int g = a + 1; g <= b; ++g) startg[g] = i; }
    if (i == N - 1) { for (int g = b + 1; g <= GBINS; ++g) startg[g] = N; }
}

__global__ __launch_bounds__(512)
void fused_kernel(const int* __restrict__ src, const int* __restrict__ dst,
                  const float2* __restrict__ pos, const int* __restrict__ startg,
                  float* __restrict__ gsum, u32* __restrict__ gcnt,
                  u32* __restrict__ done, float* __restrict__ out,
                  const int* __restrict__ nG_ptr, int E, float scale) {
    __shared__ int ss[GBINS + 1];
    __shared__ float hs[GBINS];
    __shared__ u32 hc[GBINS];
    const int tid = threadIdx.x;
    for (int i = tid; i < GBINS + 1; i += 512) ss[i] = startg[i];
    for (int i = tid; i < GBINS; i += 512) { hs[i] = 0.f; hc[i] = 0u; }
    __syncthreads();

    const int ngroups = E >> 2;            // 4 edges/thread/iter, MLP=8 gathers
    const iv4* __restrict__ s4 = (const iv4*)src;
    const iv4* __restrict__ d4 = (const iv4*)dst;
    const int gtid = blockIdx.x * 512 + tid, gstride = gridDim.x * 512;

    for (int i = gtid; i < ngroups; i += gstride) {
        const iv4 sv = __builtin_nontemporal_load(&s4[i]);
        const iv4 dv = __builtin_nontemporal_load(&d4[i]);
        float2 pa[4], pb[4];
        #pragma unroll
        for (int k = 0; k < 4; ++k) { pa[k] = pos[sv[k]]; pb[k] = pos[dv[k]]; }
        #pragma unroll
        for (int k = 0; k < 4; ++k) {
            const float dx = pb[k].x - pa[k].x;
            const float dy = pb[k].y - pa[k].y;
            const float t  = sqrtf(fmaf(dx, dx, dy * dy)) - 1.f;
            const int g = find_graph(sv[k], ss, scale);
            atomicAdd(&hs[g], t * t);      // LDS pipe: ~free under the L2 wall
            atomicAdd(&hc[g], 1u);
        }
    }
    for (int e = (ngroups << 2) + gtid; e < E; e += gstride) {   // tail (dead at E=12.8M)
        const int s = src[e], d = dst[e];
        const float2 a = pos[s], b = pos[d];
        const float dx = b.x - a.x, dy = b.y - a.y;
        const float t  = sqrtf(fmaf(dx, dx, dy * dy)) - 1.f;
        const int g = find_graph(s, ss, scale);
        atomicAdd(&hs[g], t * t);
        atomicAdd(&hc[g], 1u);
    }

    __syncthreads();
    // striped flush: rotate bin order per block to spread same-address bursts
    for (int j = tid; j < GBINS; j += 512) {
        const int g = (j + (blockIdx.x << 3)) & (GBINS - 1);
        const u32 c = hc[g];
        if (c) { atomicAdd(&gcnt[g], c); atomicAdd(&gsum[g], hs[g]); }
    }

    // merged finalize: last block to retire does the 1024-bin mean.
    __threadfence();                       // publish this block's flush atomics
    __shared__ u32 amlast;
    if (tid == 0) amlast = (atomicAdd(done, 1u) == (u32)(gridDim.x - 1)) ? 1u : 0u;
    __syncthreads();
    if (amlast) {
        const int G = *nG_ptr;
        float v = 0.f;
        for (int g = tid; g < G; g += 512) {
            // atomic-loads: device-coherent reads of other XCDs' flush results
            const float s = atomicAdd(&gsum[g], 0.f);
            const u32   c = atomicAdd(&gcnt[g], 0u);
            v += s / fmaxf((float)c, 1.f);
        }
        __shared__ float w[8];
        for (int off = 32; off; off >>= 1) v += __shfl_down(v, off, 64);
        if ((tid & 63) == 0) w[tid >> 6] = v;
        __syncthreads();
        if (tid == 0) {
            float s = 0.f;
            #pragma unroll
            for (int i2 = 0; i2 < 8; ++i2) s += w[i2];
            out[0] = s / (float)G;         // direct store: no d_out memset needed
        }
    }
}

extern "C" void kernel_launch(void* const* d_in, const int* in_sizes, int n_in,
                              void* d_out, int out_size, void* d_ws, size_t ws_size,
                              hipStream_t stream) {
    const float2* pos   = (const float2*)d_in[0];
    const int*    ei    = (const int*)d_in[1];
    const int*    batch = (const int*)d_in[2];
    const int*    nG    = (const int*)d_in[3];

    const int N = in_sizes[0] / 2;
    const int E = in_sizes[1] / 2;
    const int* src = ei;
    const int* dst = ei + E;

    // ws: [gsum 4K][gcnt 4K][startg 1025 ints][done @12800]
    float* gsum   = (float*)d_ws;
    u32*   gcnt   = (u32*)((char*)d_ws + 4096);
    int*   startg = (int*)((char*)d_ws + 8192);
    u32*   done   = (u32*)((char*)d_ws + 12800);

    const float scale = (float)GBINS / (float)N;
    prep<<<(N + 255) / 256, 256, 0, stream>>>(batch, startg, gsum, gcnt, done, N);
    // 1024 blocks = exactly 4/CU -> full 32 waves/CU residency (R10 lesson).
    fused_kernel<<<1024, 512, 0, stream>>>(src, dst, pos, startg, gsum, gcnt,
                                           done, (float*)d_out, nG, E, scale);
}

// Round 6
// 254.153 us; speedup vs baseline: 2.0078x; 2.0078x over previous
//
#include <hip/hip_runtime.h>

// EdgeVar R13: revert to R8 exactly — the verified optimum (252.5us total,
// fused 128.6us). This is the terminal structure; the session's experiments
// each falsified one alternative and confirmed R8's constraints:
//   - The wall is L2 random-request rate: 2E = 25.6M lane-gathers ~= 122us
//     pure-gather floor (R7). Request-count bound: record size doesn't matter.
//   - MLP matters: <8 outstanding gathers/thread starves the pipe (R9: +15us).
//   - Residency matters: 5000 waves vs 8192 cost +13us (R10) -- need the full
//     4 blocks/CU = 32 waves/CU. Grid MUST be 1024 x 512.
//   - Dynamic work stealing loses: same-address counter RMWs serialize waves
//     (R11: +55us). Static grid-stride partition stays.
//   - Straggler tail costs only ~2us (L2 stays saturated by the 106 blocks'
//     ~430K in-flight requests). Not worth further surgery.
//   - Merged last-block finalize (R12b) measured 3x on a visibly degraded
//     node (170 GB/s HBM, 576s npz push). Expected gain was ~5us; reverted.
//   - LDS hist atomics + boundary search ride ~free on the LDS pipe (R5).
//   - Separate passes (R7: +30us) and bucket-sorting (R3/R6: +100us) lose.
// Structure: 3 dispatches. prep (startg boundaries from sorted batch + zero
// bins), fused (gather float2 pos, LDS hist of sums+counts, striped flush),
// finalize (mean of gsum/max(gcnt,1), direct store).

typedef int iv4 __attribute__((ext_vector_type(4)));
typedef unsigned int u32;

#define GBINS 1024

__device__ __forceinline__ int find_graph(int v, const int* __restrict__ ss, float scale) {
    int g = (int)((float)v * scale);       // ~floor(v*G/N); off by a few
    g = min(g, GBINS - 1);
    while (v < ss[g]) --g;                 // ss[0]=0 guards bottom
    while (v >= ss[g + 1]) ++g;            // ss[GBINS]=N guards top
    return g;
}

// startg[1025] from sorted batch_ids; also zeros gsum/gcnt (replaces memset).
__global__ void prep(const int* __restrict__ batch, int* __restrict__ startg,
                     float* __restrict__ gsum, u32* __restrict__ gcnt, int N) {
    const int i = blockIdx.x * blockDim.x + threadIdx.x;
    if (i < GBINS) { gsum[i] = 0.f; gcnt[i] = 0u; }
    if (i >= N) return;
    const int b = batch[i];
    if (i == 0) { for (int g = 0; g <= b; ++g) startg[g] = 0; }
    else { const int a = batch[i - 1]; for (int g = a + 1; g <= b; ++g) startg[g] = i; }
    if (i == N - 1) { for (int g = b + 1; g <= GBINS; ++g) startg[g] = N; }
}

__global__ __launch_bounds__(512)
void fused_kernel(const int* __restrict__ src, const int* __restrict__ dst,
                  const float2* __restrict__ pos, const int* __restrict__ startg,
                  float* __restrict__ gsum, u32* __restrict__ gcnt,
                  int E, float scale) {
    __shared__ int ss[GBINS + 1];
    __shared__ float hs[GBINS];
    __shared__ u32 hc[GBINS];
    const int tid = threadIdx.x;
    for (int i = tid; i < GBINS + 1; i += 512) ss[i] = startg[i];
    for (int i = tid; i < GBINS; i += 512) { hs[i] = 0.f; hc[i] = 0u; }
    __syncthreads();

    const int ngroups = E >> 2;            // 4 edges/thread/iter, MLP=8 gathers
    const iv4* __restrict__ s4 = (const iv4*)src;
    const iv4* __restrict__ d4 = (const iv4*)dst;
    const int gtid = blockIdx.x * 512 + tid, gstride = gridDim.x * 512;

    for (int i = gtid; i < ngroups; i += gstride) {
        const iv4 sv = __builtin_nontemporal_load(&s4[i]);
        const iv4 dv = __builtin_nontemporal_load(&d4[i]);
        float2 pa[4], pb[4];
        #pragma unroll
        for (int k = 0; k < 4; ++k) { pa[k] = pos[sv[k]]; pb[k] = pos[dv[k]]; }
        #pragma unroll
        for (int k = 0; k < 4; ++k) {
            const float dx = pb[k].x - pa[k].x;
            const float dy = pb[k].y - pa[k].y;
            const float t  = sqrtf(fmaf(dx, dx, dy * dy)) - 1.f;
            const int g = find_graph(sv[k], ss, scale);
            atomicAdd(&hs[g], t * t);      // LDS pipe: ~free under the L2 wall
            atomicAdd(&hc[g], 1u);
        }
    }
    for (int e = (ngroups << 2) + gtid; e < E; e += gstride) {   // tail
        const int s = src[e], d = dst[e];
        const float2 a = pos[s], b = pos[d];
        const float dx = b.x - a.x, dy = b.y - a.y;
        const float t  = sqrtf(fmaf(dx, dx, dy * dy)) - 1.f;
        const int g = find_graph(s, ss, scale);
        atomicAdd(&hs[g], t * t);
        atomicAdd(&hc[g], 1u);
    }

    __syncthreads();
    // striped flush: rotate bin order per block to spread same-address bursts
    for (int j = tid; j < GBINS; j += 512) {
        const int g = (j + (blockIdx.x << 3)) & (GBINS - 1);
        const u32 c = hc[g];
        if (c) { atomicAdd(&gcnt[g], c); atomicAdd(&gsum[g], hs[g]); }
    }
}

__global__ void finalize_kernel(const float* __restrict__ gsum,
                                const u32* __restrict__ gcnt,
                                float* __restrict__ out,
                                const int* __restrict__ nG_ptr) {
    const int G = *nG_ptr;
    float v = 0.f;
    for (int g = threadIdx.x; g < G; g += blockDim.x)
        v += gsum[g] / fmaxf((float)gcnt[g], 1.f);
    __shared__ float w[16];
    for (int off = 32; off; off >>= 1) v += __shfl_down(v, off, 64);
    if ((threadIdx.x & 63) == 0) w[threadIdx.x >> 6] = v;
    __syncthreads();
    if (threadIdx.x == 0) {
        float s = 0.f;
        const int nw = (blockDim.x + 63) >> 6;
        for (int i = 0; i < nw; ++i) s += w[i];
        out[0] = s / (float)G;             // direct store: no d_out memset needed
    }
}

extern "C" void kernel_launch(void* const* d_in, const int* in_sizes, int n_in,
                              void* d_out, int out_size, void* d_ws, size_t ws_size,
                              hipStream_t stream) {
    const float2* pos   = (const float2*)d_in[0];
    const int*    ei    = (const int*)d_in[1];
    const int*    batch = (const int*)d_in[2];
    const int*    nG    = (const int*)d_in[3];

    const int N = in_sizes[0] / 2;
    const int E = in_sizes[1] / 2;
    const int* src = ei;
    const int* dst = ei + E;

    // ws: [gsum 4K][gcnt 4K][startg 1025 ints]
    float* gsum   = (float*)d_ws;
    u32*   gcnt   = (u32*)((char*)d_ws + 4096);
    int*   startg = (int*)((char*)d_ws + 8192);

    const float scale = (float)GBINS / (float)N;
    prep<<<(N + 255) / 256, 256, 0, stream>>>(batch, startg, gsum, gcnt, N);
    fused_kernel<<<1024, 512, 0, stream>>>(src, dst, pos, startg, gsum, gcnt, E, scale);
    finalize_kernel<<<1, 1024, 0, stream>>>(gsum, gcnt, (float*)d_out, nG);
}